// Round 5
// baseline (273.525 us; speedup 1.0000x reference)
//
#include <hip/hip_runtime.h>
#include <hip/hip_bf16.h>
#include <cstdint>
#include <type_traits>

// Problem constants (reference: N=8192, D=2048, M=512, E=4, SCALE=1)
#define N_TOK 8192
#define DDIM  2048
#define MDIM  512
#define NEXP  4
#define PADROWS (N_TOK + NEXP * 256)   // expert ranges padded to 256 -> 9216

typedef __bf16 bf16x4 __attribute__((ext_vector_type(4)));
typedef __bf16 bf16x8 __attribute__((ext_vector_type(8)));
typedef float  f32x4  __attribute__((ext_vector_type(4)));

// ---------------------------------------------------------------------------
// Scratch (module device globals, fully rewritten every call).
// GEMM-staged tensors stored K-tiled at 32: [kt32][row][32] -> one staging
// pass (THREADS/4 rows x 32 k) is fully contiguous; every global_load_lds
// is a contiguous 1KB-per-wave burst (r4 proved contiguity is the lever:
// r3 scattered 147us -> r4 contiguous 47us for gemm2).
// ---------------------------------------------------------------------------
__device__ int g_counts[NEXP];
__device__ int g_idx[NEXP * N_TOK];
__device__ __align__(16) __hip_bfloat16 g_Xp[(size_t)DDIM * PADROWS];       // 37.7 MB
__device__ __align__(16) __hip_bfloat16 g_Hp[(size_t)MDIM * PADROWS];       //  9.4 MB
__device__ __align__(16) __hip_bfloat16 g_W1t[(size_t)NEXP * MDIM * DDIM];  //  8.4 MB
__device__ __align__(16) __hip_bfloat16 g_W2t[(size_t)NEXP * DDIM * MDIM];  //  8.4 MB

__global__ void zero_counts_kernel() {
    if (threadIdx.x < NEXP) g_counts[threadIdx.x] = 0;
}

// ---------------------------------------------------------------------------
// Bucket tokens by expert — wave-aggregated atomics (verified r1-r4).
// ---------------------------------------------------------------------------
__global__ void bucket_kernel(const void* __restrict__ domv) {
    const int i    = blockIdx.x * blockDim.x + threadIdx.x;
    const int lane = threadIdx.x & 63;

    const long long* d64 = (const long long*)domv;
    long long probe = d64[lane];
    bool mode64 = (__ballot(probe >= 0 && probe < NEXP) == ~0ull);

    const int e = mode64 ? (int)d64[i] : ((const int*)domv)[i];

#pragma unroll
    for (int ex = 0; ex < NEXP; ++ex) {
        unsigned long long m = __ballot(e == ex);
        if (m == 0) continue;
        int cnt    = __popcll(m);
        int leader = __ffsll((long long)m) - 1;
        int base   = 0;
        if (lane == leader) base = atomicAdd(&g_counts[ex], cnt);
        base = __shfl(base, leader);
        if (e == ex) {
            int prefix = __popcll(m & ((1ull << lane) - 1ull));
            g_idx[ex * N_TOK + base + prefix] = i;
        }
    }
}

// ---------------------------------------------------------------------------
// Combined convert pass (ONE launch):
//  y=0: x gather-permute-convert -> g_Xp [kt32][slot][32], expert-sorted slots
//  y=1: W1 -> g_W1t [(e*64+kt32)*512+m][32];  W2 -> g_W2t [(e*16+kt32)*2048+d][32]
// ---------------------------------------------------------------------------
__global__ __launch_bounds__(256)
void cvt_all_kernel(const float* __restrict__ x,
                    const float* __restrict__ w1,
                    const float* __restrict__ w2) {
    if (blockIdx.y == 0) {
        int c[NEXP], off[NEXP + 1]; off[0] = 0;
#pragma unroll
        for (int e = 0; e < NEXP; ++e) { c[e] = g_counts[e]; off[e + 1] = off[e] + ((c[e] + 255) & ~255); }
        const int gs = blockIdx.x;
        int e = 0;
#pragma unroll
        for (int t = 0; t < NEXP - 1; ++t) if (gs >= off[t + 1]) e = t + 1;
        if (gs >= off[e + 1]) return;
        int ls = gs - off[e];
        if (ls >= c[e]) ls = c[e] - 1;
        if (ls < 0) ls = 0;
        const int tok = g_idx[e * N_TOK + ls];

        const int d0 = threadIdx.x * 8;
        const float* s = x + (size_t)tok * DDIM + d0;
        f32x4 a = *(const f32x4*)s;
        f32x4 b = *(const f32x4*)(s + 4);
        bf16x8 r;
        r[0] = (__bf16)a[0]; r[1] = (__bf16)a[1]; r[2] = (__bf16)a[2]; r[3] = (__bf16)a[3];
        r[4] = (__bf16)b[0]; r[5] = (__bf16)b[1]; r[6] = (__bf16)b[2]; r[7] = (__bf16)b[3];
        *(bf16x8*)&g_Xp[((size_t)(d0 >> 5) * PADROWS + gs) * 32 + (d0 & 31)] = r;
    } else {
        constexpr int HALF = NEXP * MDIM * DDIM / 8;       // 524288 groups
        const int gtid = blockIdx.x * 256 + threadIdx.x;
        if (gtid >= 2 * HALF) return;
        const bool is1 = (gtid < HALF);
        const int g8 = is1 ? gtid : gtid - HALF;
        const float* src = is1 ? w1 : w2;
        __hip_bfloat16* dst = is1 ? g_W1t : g_W2t;

        const int e   = g8 >> 17;                          // 131072 groups/expert
        const int rem = g8 & 131071;
        int row, kt, within;
        if (is1) { row = rem >> 8; int d0 = (rem & 255) * 8; kt = d0 >> 5; within = d0 & 31; }
        else     { row = rem >> 6; int m0 = (rem & 63) * 8;  kt = m0 >> 5; within = m0 & 31; }
        const float* s = src + (size_t)g8 * 8;
        f32x4 a = *(const f32x4*)s;
        f32x4 b = *(const f32x4*)(s + 4);
        bf16x8 r;
        r[0] = (__bf16)a[0]; r[1] = (__bf16)a[1]; r[2] = (__bf16)a[2]; r[3] = (__bf16)a[3];
        r[4] = (__bf16)b[0]; r[5] = (__bf16)b[1]; r[6] = (__bf16)b[2]; r[7] = (__bf16)b[3];
        const size_t d = is1 ? (((size_t)(e * 64 + kt) * MDIM + row) * 32 + within)
                             : (((size_t)(e * 16 + kt) * DDIM + row) * 32 + within);
        *(bf16x8*)&dst[d] = r;
    }
}

// ---------------------------------------------------------------------------
// global -> LDS direct DMA, 16B/lane (wave-uniform LDS base + lane*16).
// ---------------------------------------------------------------------------
__device__ __forceinline__ void gl16(const __hip_bfloat16* g, __hip_bfloat16* l) {
    __builtin_amdgcn_global_load_lds(
        (const __attribute__((address_space(1))) void*)g,
        (__attribute__((address_space(3))) void*)l,
        16, 0, 0);
}

// counted vmcnt (T4): literal immediates via constexpr dispatch
template <int N>
__device__ __forceinline__ void wait_vm() {
    if constexpr (N == 0)       asm volatile("s_waitcnt vmcnt(0)" ::: "memory");
    else if constexpr (N == 4)  asm volatile("s_waitcnt vmcnt(4)" ::: "memory");
    else if constexpr (N == 8)  asm volatile("s_waitcnt vmcnt(8)" ::: "memory");
    else if constexpr (N == 12) asm volatile("s_waitcnt vmcnt(12)" ::: "memory");
}

// ---------------------------------------------------------------------------
// Grouped NT GEMM, quad-buffered 3-tile-lookahead pipeline (round-5 change).
//   r4 counters: MFMA-busy == ideal but delivery ran at 10.5 B/cy/CU vs the
//   ~20 B/cy/CU m97/m201 achieve. 2-buf issued one load burst per step then
//   idled; 4 buffers + wait vmcnt(3*LPS) keeps ~96-128KB/CU in flight and
//   gives every tile 3 iterations of completion slack.
// BK=32 (one 16x16x32 MFMA k-slice per step); per K-step per thread: 2 A +
// 2 B gl16 (LPS=4). Waits: 12 steady, 8/4/0 on the last three tiles.
// LDS swizzle for 64B rows: LDS[row][s] = global[row][s ^ ((row>>1)&3)];
// producer source slot (l&3)^((l>>3)&3), consumer slot (lane>>4)^((lane>>1)&3)
// -> uniform 8 word-accesses/bank = conflict-free (LDS minimum).
// Grid: 1D, XCD-partitioned swizzle (nwg%8==0): swz=(bid&7)*(nwg/8)+(bid>>3),
// rt=swz%NRT, ct=swz/NRT -> each XCD owns a ct-stripe; its W-slice (1-2MB)
// stays L2-resident, removing B-staging from the L3 path.
// MFMA operands SWAPPED (mfma(b,a)): lane holds 4 consecutive C-cols of one
// slot row -> f32x4 epilogue (r2-r4 verified).
// ---------------------------------------------------------------------------
template <int BM, int BN, int NWAVE, int WVN, int KDIM, int NCOLS,
          bool RELU, bool TILEOUT, typename TC>
__device__ __forceinline__ void gemm_core(const __hip_bfloat16* __restrict__ A,
                                          const __hip_bfloat16* __restrict__ B,
                                          const float* __restrict__ bias,
                                          const float* __restrict__ resid,
                                          TC* __restrict__ C) {
    constexpr int BK      = 32;
    constexpr int KT      = KDIM / BK;
    constexpr int THREADS = NWAVE * 64;
    constexpr int RPP     = THREADS / 4;       // rows per staging pass
    constexpr int APASS   = BM / RPP;
    constexpr int BPASS   = BN / RPP;
    constexpr int WM      = BM / (NWAVE / WVN);
    constexpr int WN      = BN / WVN;
    constexpr int NI      = WM / 16;
    constexpr int NJ      = WN / 16;
    constexpr int NRT     = PADROWS / BM;
    constexpr int NWG     = NRT * (NCOLS / BN);
    static_assert(NWG % 8 == 0, "bijective XCD swizzle needs nwg%8==0");

    // XCD-partitioned block swizzle
    const int bid = blockIdx.x;
    const int swz = (bid & 7) * (NWG / 8) + (bid >> 3);
    const int rt  = swz % NRT;
    const int ct  = swz / NRT;

    int cv[NEXP], off[NEXP + 1]; off[0] = 0;
#pragma unroll
    for (int x = 0; x < NEXP; ++x) { cv[x] = g_counts[x]; off[x + 1] = off[x] + ((cv[x] + 255) & ~255); }
    const int r0 = rt * BM;
    if (r0 >= off[NEXP]) return;               // uniform across block
    int e = 0;
#pragma unroll
    for (int t = 0; t < NEXP - 1; ++t) if (r0 >= off[t + 1]) e = t + 1;

    __shared__ __align__(16) __hip_bfloat16 sA[4][BM * BK];
    __shared__ __align__(16) __hip_bfloat16 sB[4][BN * BK];
    __shared__ int sTok[BM];

    const int tid  = threadIdx.x;
    const int wave = tid >> 6;
    const int lane = tid & 63;

    if (!TILEOUT) {                            // token map only for epilogue
        if (tid < BM) {
            int ls = r0 + tid - off[e];
            sTok[tid] = (ls < cv[e]) ? g_idx[e * N_TOK + ls] : -1;
        }
    }

    // staging addresses: pass p covers rows [p*RPP, p*RPP+RPP);
    // lane l -> row p*RPP + wave*16 + (l>>2), source slot (l&3)^((l>>3)&3)
    const int srow = wave * 16 + (lane >> 2);
    const int ssl  = ((lane & 3) ^ ((lane >> 3) & 3)) * 8;

    auto stage = [&](int buf, int kt) {
#pragma unroll
        for (int p = 0; p < APASS; ++p)
            gl16(A + ((size_t)kt * PADROWS + r0 + p * RPP + srow) * BK + ssl,
                 &sA[buf][(p * RPP + wave * 16) * BK]);
#pragma unroll
        for (int p = 0; p < BPASS; ++p)
            gl16(B + ((size_t)(e * KT + kt) * NCOLS + ct * BN + p * RPP + srow) * BK + ssl,
                 &sB[buf][(p * RPP + wave * 16) * BK]);
    };

    // fragment read addresses
    const int wm   = (wave / WVN) * WM;
    const int wn   = (wave % WVN) * WN;
    const int frow = lane & 15;
    const int cof  = (((lane >> 4) ^ ((lane >> 1) & 3))) * 8;  // swizzled k-slot

    f32x4 acc[NI][NJ] = {};

    auto compute = [&](int buf) {
        const __hip_bfloat16* pA = &sA[buf][0];
        const __hip_bfloat16* pB = &sB[buf][0];
        bf16x8 bfr[NJ];
#pragma unroll
        for (int j = 0; j < NJ; ++j)
            bfr[j] = *(const bf16x8*)&pB[(wn + j * 16 + frow) * BK + cof];
#pragma unroll
        for (int i = 0; i < NI; ++i) {
            bf16x8 af = *(const bf16x8*)&pA[(wm + i * 16 + frow) * BK + cof];
#pragma unroll
            for (int j = 0; j < NJ; ++j)       // SWAPPED operands
                acc[i][j] = __builtin_amdgcn_mfma_f32_16x16x32_bf16(
                    bfr[j], af, acc[i][j], 0, 0, 0);
        }
    };

    stage(0, 0); stage(1, 1); stage(2, 2); stage(3, 3);

    for (int t = 0; t < KT; ++t) {
        const int rem = KT - 1 - t;
        if (rem >= 3)      wait_vm<12>();      // tile t done; t+1..t+3 in flight
        else if (rem == 2) wait_vm<8>();
        else if (rem == 1) wait_vm<4>();
        else               wait_vm<0>();
        __builtin_amdgcn_s_barrier();          // block-wide: tile t fully in LDS
        __builtin_amdgcn_sched_barrier(0);
        compute(t & 3);
        asm volatile("" ::: "memory");         // pin ds_reads above the barrier
        __builtin_amdgcn_s_barrier();          // all waves done reading buf
        if (t + 4 < KT) stage(t & 3, t + 4);
    }

    // epilogue — swapped-operand layout: acc[i][j][r]:
    //   slot row = r0 + wm + i*16 + (lane&15)
    //   C column = ct*BN + wn + j*16 + (lane>>4)*4 + r
    const int lrow = lane & 15;
    const int lcol = (lane >> 4) * 4;
#pragma unroll
    for (int i = 0; i < NI; ++i) {
        const int rl = wm + i * 16 + lrow;
        const int gs = r0 + rl;
#pragma unroll
        for (int j = 0; j < NJ; ++j) {
            const int col = ct * BN + wn + j * 16 + lcol;
            const f32x4 bv = *(const f32x4*)&bias[(size_t)e * NCOLS + col];
            f32x4 v = acc[i][j] + bv;
            if (RELU) {
#pragma unroll
                for (int r = 0; r < 4; ++r) v[r] = fmaxf(v[r], 0.0f);
            }
            if constexpr (TILEOUT) {
                // K-tiled slot-order write (coalesced; pad rows defined)
                bf16x4 h;
                h[0] = (__bf16)v[0]; h[1] = (__bf16)v[1];
                h[2] = (__bf16)v[2]; h[3] = (__bf16)v[3];
                *(bf16x4*)&C[((size_t)(col >> 5) * PADROWS + gs) * 32 + (col & 31)] = h;
            } else {
                const int tk = sTok[rl];
                if (tk >= 0) {
                    v += *(const f32x4*)&resid[(size_t)tk * NCOLS + col];
                    *(f32x4*)&C[(size_t)tk * NCOLS + col] = v;
                }
            }
        }
    }
}

// GEMM1: Hp = relu(Xp @ W1t[e]^T + b1[e])  [K=2048, cols=512]
// 128x128, 4 waves (2x2, wave 64x64), KT=64, LDS 64KB -> 2 blocks/CU,
// grid 72x4 = 288. Per-XCD W1t ct-slice = 2MB -> L2-resident.
__global__ __launch_bounds__(256, 2)
void gemm1_kernel(const float* __restrict__ b1) {
    gemm_core<128, 128, 4, 2, DDIM, MDIM, true, true, __hip_bfloat16>(
        g_Xp, g_W1t, b1, nullptr, g_Hp);
}

// GEMM2: out[tok] = x[tok] + Hp @ W2t[e]^T + b2[e]  [K=512, cols=2048]
// 256x256, 8 waves (2x4, wave 128x64), KT=16, LDS 128KB -> 1 block/CU,
// grid 36x8 = 288. Per-XCD W2t ct-slice = 1MB -> L2-resident.
__global__ __launch_bounds__(512, 2)
void gemm2_kernel(const float* __restrict__ x,
                  const float* __restrict__ b2,
                  float* __restrict__ out) {
    gemm_core<256, 256, 8, 4, MDIM, DDIM, false, false, float>(
        g_Hp, g_W2t, b2, x, out);
}

extern "C" void kernel_launch(void* const* d_in, const int* in_sizes, int n_in,
                              void* d_out, int out_size, void* d_ws, size_t ws_size,
                              hipStream_t stream) {
    const float* x  = (const float*)d_in[0];
    const void*  dm = d_in[1];
    const float* W1 = (const float*)d_in[2];
    const float* b1 = (const float*)d_in[3];
    const float* W2 = (const float*)d_in[4];
    const float* b2 = (const float*)d_in[5];
    float* out = (float*)d_out;

    zero_counts_kernel<<<1, 64, 0, stream>>>();
    bucket_kernel<<<N_TOK / 256, 256, 0, stream>>>(dm);
    cvt_all_kernel<<<dim3(PADROWS, 2), 256, 0, stream>>>(x, W1, W2);

    gemm1_kernel<<<72 * 4, 256, 0, stream>>>(b1);
    gemm2_kernel<<<36 * 8, 512, 0, stream>>>(x, b2, out);
}